// Round 7
// baseline (89.109 us; speedup 1.0000x reference)
//
#include <hip/hip_runtime.h>

// Weighted order statistic, B=4,C=3,K=3,NC=16,H=W=128, D=27, MD=54.
// One thread per (pixel, nc).
//  - 27 keys = f2key(mask+patch): exact 32-bit monotone float->uint map.
//  - Payload = the TWO weights (w+ = weight[nc][d], w- = weight[nc][d+27])
//    carried through a Batcher merge-exchange sort of 32 slots (5 zero
//    sentinels), DESCENDING, 191 compare-exchanges.
//  - Sign-pair trick: the -m list sorted ascending is slot-wise ~key with
//    payload w-; one 64-wide bitonic merge (desc ++ asc, 192 CEs) yields the
//    full 54-candidate descending order (5x 0xFFFFFFFF sentinel complements
//    land at positions 0..4, 5x zero-keys at 59..63).
//  - Walk positions 5..58: inclusive f32 cumsum of the carried weights in
//    EXACT sorted order (bit-identical add sequence to the reference's
//    jnp.cumsum); select last position with acc <= bias; fallback = pos 5
//    (max candidate, li clipped to 0). No LDS gather in the walk.
// Everything is NAMED SCALARS (no arrays) so regalloc cannot demote to
// scratch/AGPR shuffles; amdgpu_waves_per_eu(2,2) gives a 256-VGPR budget.
// Output layout: reference reshapes (b*hw, NC) -> (b,NC,h,w) without
// transpose, so flat order is (b, hw, nc) -> out[n*NCH + nc].

#define NCH 16
#define DD  27
#define MDD 54
#define HH  128
#define WW  128
#define CCH 3

__device__ __forceinline__ unsigned f2key(unsigned bits) {
  const unsigned s = (unsigned)((int)bits >> 31);
  return bits ^ (s | 0x80000000u);
}

// compare-exchange, descending, key + dual weight payload (sort phase)
#define CES(i,j) { const bool s_ = k##i < k##j; \
  const unsigned tk_ = s_ ? k##j : k##i; k##j = s_ ? k##i : k##j; k##i = tk_; \
  const float ta_ = s_ ? a##j : a##i; a##j = s_ ? a##i : a##j; a##i = ta_;     \
  const float tb_ = s_ ? b##j : b##i; b##j = s_ ? b##i : b##j; b##i = tb_; }

// compare-exchange, descending, key + single weight payload (merge phase)
#define CEM(i,j) { const bool s_ = k##i < k##j; \
  const unsigned tk_ = s_ ? k##j : k##i; k##j = s_ ? k##i : k##j; k##i = tk_; \
  const float tu_ = s_ ? u##j : u##i; u##j = s_ ? u##i : u##j; u##i = tu_; }

#define BLD(i) const float m##i = mrow[i] + prow[i]; \
  unsigned k##i = f2key(__float_as_uint(m##i)); \
  float a##i = wrow[i]; float b##i = wrow[DD + i];

#define WK(p) { acc += u##p; ykey = (acc <= t) ? k##p : ykey; }

__global__ void __attribute__((amdgpu_flat_work_group_size(256, 256),
                               amdgpu_waves_per_eu(2, 2)))
wos_kernel(const float* __restrict__ xin,
           const float* __restrict__ mask,
           const float* __restrict__ weight,
           const float* __restrict__ bias,
           float* __restrict__ out)
{
  __shared__ float mL[NCH][28];
  __shared__ float wS[NCH * MDD];
  __shared__ float bL[NCH];
  __shared__ float pL[16][28];

  const int tid = threadIdx.x;
  for (int i = tid; i < NCH * DD; i += 256) mL[i / DD][i % DD] = mask[i];
  for (int i = tid; i < NCH * MDD; i += 256) wS[i] = weight[i];
  if (tid < NCH) bL[tid] = bias[tid];

  const int nc   = tid & 15;
  const int pix  = tid >> 4;
  const int base = (int)blockIdx.x * 16;

  // cooperative patch staging: 16 pixels x 27 taps, 'same' zero padding
  for (int i = tid; i < 16 * DD; i += 256) {
    const int pp = i / DD;
    const int d  = i - pp * DD;
    const int nn = base + pp;
    const int bb = nn >> 14;
    const int rr = nn & 16383;
    const int yy = rr >> 7;
    const int xx = rr & 127;
    const int c  = d / 9;
    const int ij = d - c * 9;
    const int di = ij / 3;
    const int dj = ij - di * 3;
    const int ys = yy + di - 1;
    const int xs = xx + dj - 1;
    const bool ok = ((unsigned)ys < (unsigned)HH) && ((unsigned)xs < (unsigned)WW);
    pL[pp][d] = ok ? xin[((bb * CCH + c) * HH + ys) * WW + xs] : 0.0f;
  }
  __syncthreads();

  const float* mrow = &mL[nc][0];
  const float* prow = &pL[pix][0];
  const float* wrow = &wS[nc * MDD];
  const float  t    = bL[nc];

  BLD(0) BLD(1) BLD(2) BLD(3) BLD(4) BLD(5) BLD(6) BLD(7) BLD(8)
  BLD(9) BLD(10) BLD(11) BLD(12) BLD(13) BLD(14) BLD(15) BLD(16) BLD(17)
  BLD(18) BLD(19) BLD(20) BLD(21) BLD(22) BLD(23) BLD(24) BLD(25) BLD(26)
  unsigned k27 = 0u, k28 = 0u, k29 = 0u, k30 = 0u, k31 = 0u;
  float a27 = 0.f, a28 = 0.f, a29 = 0.f, a30 = 0.f, a31 = 0.f;
  float b27 = 0.f, b28 = 0.f, b29 = 0.f, b30 = 0.f, b31 = 0.f;

  // ---- Batcher merge-exchange sort, n=32, descending (191 CEs) ----
  // P1 (p=16,d=16,r=0)
  CES(0,16) CES(1,17) CES(2,18) CES(3,19) CES(4,20) CES(5,21) CES(6,22) CES(7,23)
  CES(8,24) CES(9,25) CES(10,26) CES(11,27) CES(12,28) CES(13,29) CES(14,30) CES(15,31)
  // P2 (p=8,d=8,r=0)
  CES(0,8) CES(1,9) CES(2,10) CES(3,11) CES(4,12) CES(5,13) CES(6,14) CES(7,15)
  CES(16,24) CES(17,25) CES(18,26) CES(19,27) CES(20,28) CES(21,29) CES(22,30) CES(23,31)
  // P3 (p=8,d=8,r=8)
  CES(8,16) CES(9,17) CES(10,18) CES(11,19) CES(12,20) CES(13,21) CES(14,22) CES(15,23)
  // P4 (p=4,d=4,r=0)
  CES(0,4) CES(1,5) CES(2,6) CES(3,7) CES(8,12) CES(9,13) CES(10,14) CES(11,15)
  CES(16,20) CES(17,21) CES(18,22) CES(19,23) CES(24,28) CES(25,29) CES(26,30) CES(27,31)
  // P5 (p=4,d=12,r=4)
  CES(4,16) CES(5,17) CES(6,18) CES(7,19) CES(12,24) CES(13,25) CES(14,26) CES(15,27)
  // P6 (p=4,d=4,r=4)
  CES(4,8) CES(5,9) CES(6,10) CES(7,11) CES(12,16) CES(13,17) CES(14,18) CES(15,19)
  CES(20,24) CES(21,25) CES(22,26) CES(23,27)
  // P7 (p=2,d=2,r=0)
  CES(0,2) CES(1,3) CES(4,6) CES(5,7) CES(8,10) CES(9,11) CES(12,14) CES(13,15)
  CES(16,18) CES(17,19) CES(20,22) CES(21,23) CES(24,26) CES(25,27) CES(28,30) CES(29,31)
  // P8 (p=2,d=14,r=2)
  CES(2,16) CES(3,17) CES(6,20) CES(7,21) CES(10,24) CES(11,25) CES(14,28) CES(15,29)
  // P9 (p=2,d=6,r=2)
  CES(2,8) CES(3,9) CES(6,12) CES(7,13) CES(10,16) CES(11,17) CES(14,20) CES(15,21)
  CES(18,24) CES(19,25) CES(22,28) CES(23,29)
  // P10 (p=2,d=2,r=2)
  CES(2,4) CES(3,5) CES(6,8) CES(7,9) CES(10,12) CES(11,13) CES(14,16) CES(15,17)
  CES(18,20) CES(19,21) CES(22,24) CES(23,25) CES(26,28) CES(27,29)
  // P11 (p=1,d=1,r=0)
  CES(0,1) CES(2,3) CES(4,5) CES(6,7) CES(8,9) CES(10,11) CES(12,13) CES(14,15)
  CES(16,17) CES(18,19) CES(20,21) CES(22,23) CES(24,25) CES(26,27) CES(28,29) CES(30,31)
  // P12 (p=1,d=15,r=1)
  CES(1,16) CES(3,18) CES(5,20) CES(7,22) CES(9,24) CES(11,26) CES(13,28) CES(15,30)
  // P13 (p=1,d=7,r=1)
  CES(1,8) CES(3,10) CES(5,12) CES(7,14) CES(9,16) CES(11,18) CES(13,20) CES(15,22)
  CES(17,24) CES(19,26) CES(21,28) CES(23,30)
  // P14 (p=1,d=3,r=1)
  CES(1,4) CES(3,6) CES(5,8) CES(7,10) CES(9,12) CES(11,14) CES(13,16) CES(15,18)
  CES(17,20) CES(19,22) CES(21,24) CES(23,26) CES(25,28) CES(27,30)
  // P15 (p=1,d=1,r=1)
  CES(1,2) CES(3,4) CES(5,6) CES(7,8) CES(9,10) CES(11,12) CES(13,14) CES(15,16)
  CES(17,18) CES(19,20) CES(21,22) CES(23,24) CES(25,26) CES(27,28) CES(29,30)

  // ---- build 64-slot merge input: top = sorted +m (w+), bottom = ~key (w-) ----
  unsigned k32=~k0, k33=~k1, k34=~k2, k35=~k3, k36=~k4, k37=~k5, k38=~k6, k39=~k7,
           k40=~k8, k41=~k9, k42=~k10,k43=~k11,k44=~k12,k45=~k13,k46=~k14,k47=~k15,
           k48=~k16,k49=~k17,k50=~k18,k51=~k19,k52=~k20,k53=~k21,k54=~k22,k55=~k23,
           k56=~k24,k57=~k25,k58=~k26,k59=~k27,k60=~k28,k61=~k29,k62=~k30,k63=~k31;
  float u0=a0,  u1=a1,  u2=a2,  u3=a3,  u4=a4,  u5=a5,  u6=a6,  u7=a7,
        u8=a8,  u9=a9,  u10=a10,u11=a11,u12=a12,u13=a13,u14=a14,u15=a15,
        u16=a16,u17=a17,u18=a18,u19=a19,u20=a20,u21=a21,u22=a22,u23=a23,
        u24=a24,u25=a25,u26=a26,u27=a27,u28=a28,u29=a29,u30=a30,u31=a31;
  float u32=b0, u33=b1, u34=b2, u35=b3, u36=b4, u37=b5, u38=b6, u39=b7,
        u40=b8, u41=b9, u42=b10,u43=b11,u44=b12,u45=b13,u46=b14,u47=b15,
        u48=b16,u49=b17,u50=b18,u51=b19,u52=b20,u53=b21,u54=b22,u55=b23,
        u56=b24,u57=b25,u58=b26,u59=b27,u60=b28,u61=b29,u62=b30,u63=b31;

  // ---- bitonic merge of 64 (desc ++ asc), descending, 192 CEs ----
  CEM(0,32) CEM(1,33) CEM(2,34) CEM(3,35) CEM(4,36) CEM(5,37) CEM(6,38) CEM(7,39)
  CEM(8,40) CEM(9,41) CEM(10,42) CEM(11,43) CEM(12,44) CEM(13,45) CEM(14,46) CEM(15,47)
  CEM(16,48) CEM(17,49) CEM(18,50) CEM(19,51) CEM(20,52) CEM(21,53) CEM(22,54) CEM(23,55)
  CEM(24,56) CEM(25,57) CEM(26,58) CEM(27,59) CEM(28,60) CEM(29,61) CEM(30,62) CEM(31,63)

  CEM(0,16) CEM(1,17) CEM(2,18) CEM(3,19) CEM(4,20) CEM(5,21) CEM(6,22) CEM(7,23)
  CEM(8,24) CEM(9,25) CEM(10,26) CEM(11,27) CEM(12,28) CEM(13,29) CEM(14,30) CEM(15,31)
  CEM(32,48) CEM(33,49) CEM(34,50) CEM(35,51) CEM(36,52) CEM(37,53) CEM(38,54) CEM(39,55)
  CEM(40,56) CEM(41,57) CEM(42,58) CEM(43,59) CEM(44,60) CEM(45,61) CEM(46,62) CEM(47,63)

  CEM(0,8) CEM(1,9) CEM(2,10) CEM(3,11) CEM(4,12) CEM(5,13) CEM(6,14) CEM(7,15)
  CEM(16,24) CEM(17,25) CEM(18,26) CEM(19,27) CEM(20,28) CEM(21,29) CEM(22,30) CEM(23,31)
  CEM(32,40) CEM(33,41) CEM(34,42) CEM(35,43) CEM(36,44) CEM(37,45) CEM(38,46) CEM(39,47)
  CEM(48,56) CEM(49,57) CEM(50,58) CEM(51,59) CEM(52,60) CEM(53,61) CEM(54,62) CEM(55,63)

  CEM(0,4) CEM(1,5) CEM(2,6) CEM(3,7) CEM(8,12) CEM(9,13) CEM(10,14) CEM(11,15)
  CEM(16,20) CEM(17,21) CEM(18,22) CEM(19,23) CEM(24,28) CEM(25,29) CEM(26,30) CEM(27,31)
  CEM(32,36) CEM(33,37) CEM(34,38) CEM(35,39) CEM(40,44) CEM(41,45) CEM(42,46) CEM(43,47)
  CEM(48,52) CEM(49,53) CEM(50,54) CEM(51,55) CEM(56,60) CEM(57,61) CEM(58,62) CEM(59,63)

  CEM(0,2) CEM(1,3) CEM(4,6) CEM(5,7) CEM(8,10) CEM(9,11) CEM(12,14) CEM(13,15)
  CEM(16,18) CEM(17,19) CEM(20,22) CEM(21,23) CEM(24,26) CEM(25,27) CEM(28,30) CEM(29,31)
  CEM(32,34) CEM(33,35) CEM(36,38) CEM(37,39) CEM(40,42) CEM(41,43) CEM(44,46) CEM(45,47)
  CEM(48,50) CEM(49,51) CEM(52,54) CEM(53,55) CEM(56,58) CEM(57,59) CEM(60,62) CEM(61,63)

  CEM(0,1) CEM(2,3) CEM(4,5) CEM(6,7) CEM(8,9) CEM(10,11) CEM(12,13) CEM(14,15)
  CEM(16,17) CEM(18,19) CEM(20,21) CEM(22,23) CEM(24,25) CEM(26,27) CEM(28,29) CEM(30,31)
  CEM(32,33) CEM(34,35) CEM(36,37) CEM(38,39) CEM(40,41) CEM(42,43) CEM(44,45) CEM(46,47)
  CEM(48,49) CEM(50,51) CEM(52,53) CEM(54,55) CEM(56,57) CEM(58,59) CEM(60,61) CEM(62,63)

  // ---- walk positions 5..58: exact-order f32 cumsum + select ----
  float acc = 0.0f;
  unsigned ykey = k5;
  WK(5) WK(6) WK(7) WK(8) WK(9) WK(10) WK(11) WK(12) WK(13) WK(14)
  WK(15) WK(16) WK(17) WK(18) WK(19) WK(20) WK(21) WK(22) WK(23) WK(24)
  WK(25) WK(26) WK(27) WK(28) WK(29) WK(30) WK(31) WK(32) WK(33) WK(34)
  WK(35) WK(36) WK(37) WK(38) WK(39) WK(40) WK(41) WK(42) WK(43) WK(44)
  WK(45) WK(46) WK(47) WK(48) WK(49) WK(50) WK(51) WK(52) WK(53) WK(54)
  WK(55) WK(56) WK(57) WK(58)

  const unsigned bits = (ykey & 0x80000000u) ? (ykey ^ 0x80000000u) : ~ykey;
  out[(base + pix) * NCH + nc] = __uint_as_float(bits);
}

extern "C" void kernel_launch(void* const* d_in, const int* in_sizes, int n_in,
                              void* d_out, int out_size, void* d_ws, size_t ws_size,
                              hipStream_t stream) {
  const float* x      = (const float*)d_in[0];
  const float* mask   = (const float*)d_in[1];
  const float* weight = (const float*)d_in[2];
  const float* bias   = (const float*)d_in[3];
  float* outp = (float*)d_out;

  dim3 grid(4096);   // 65536 pixels / 16 per block
  dim3 block(256);   // 16 pixels x 16 channels
  hipLaunchKernelGGL(wos_kernel, grid, block, 0, stream, x, mask, weight, bias, outp);
}

// Round 8
// 66.641 us; speedup vs baseline: 1.3371x; 1.3371x over previous
//
#include <hip/hip_runtime.h>

// Weighted order statistic, B=4,C=3,K=3,NC=16,H=W=128, D=27, MD=54.
// One thread per (pixel, nc). Pipeline (R5's verified ordering construction,
// restructured to halve peak register live-set):
//   1) tables staged TRANSPOSED: mT[27][16], wT[54][16] (16 lanes -> 16 banks,
//      broadcast across pix groups -> conflict-free); pL[16][28] (broadcast).
//   2) 27 keys = f2key(mask+patch) (exact 32-bit monotone map) + index payload;
//      Batcher merge-exchange sort of 32 slots (5 zero sentinels), DESC, 191 CEs.
//   3) sign-split per sorted slot i: tk=max(k,~k) (|m| side, 5x 0xFFFFFFFF
//      sentinels -> merged positions 0..4), tw = weight idx of the taken side;
//      bottom half (bk=~tk, bw = other side's idx) is PARKED in LDS
//      (27 keys + 27x6-bit indices packed 4-per-dword; row stride 37 dwords
//      -> 2-way max bank aliasing = free) so it is NOT live during top phase.
//   4) top: 32-wide bitonic merge desc (keys + tw), walk positions 5..31 with
//      weight gather wT[tw][nc]; f32 inclusive cumsum in EXACT sorted order.
//   5) reload park, bottom: 32-wide merge (5 zero-key sentinels sink to
//      27..31), walk positions 0..26 continuing the SAME acc chain ->
//      bit-identical add sequence to the reference's jnp.cumsum.
//   6) select last position with acc <= bias; fallback = top position 5
//      (max candidate, li clipped to 0). Exact inverse f2key -> value.
// Output layout: reference reshapes (b*hw, NC) -> (b,NC,h,w) without
// transpose, so flat order is (b, hw, nc) -> out[n*NCH + nc].

#define NCH 16
#define DD  27
#define MDD 54
#define HH  128
#define WW  128
#define CCH 3
#define PSTR 37   // park row stride (dwords); 37 mod 32 = 5, gcd=1 -> 2-way max

__device__ __forceinline__ unsigned f2key(unsigned bits) {
  const unsigned s = (unsigned)((int)bits >> 31);
  return bits ^ (s | 0x80000000u);
}

__global__ __launch_bounds__(256) void wos_kernel(
    const float* __restrict__ xin,
    const float* __restrict__ mask,
    const float* __restrict__ weight,
    const float* __restrict__ bias,
    float* __restrict__ out)
{
  __shared__ float    mT[DD][NCH];        // mask transposed [d][nc]
  __shared__ float    wT[MDD][NCH];       // weights transposed [idx][nc]
  __shared__ float    pL[16][DD + 1];     // patches (reads broadcast per pix)
  __shared__ float    bL[NCH];
  __shared__ unsigned park[256 * PSTR];   // per-thread: 27 bk + 7 packed bw

  const int tid = threadIdx.x;
  for (int i = tid; i < NCH * DD; i += 256) {
    const int ncs = i / DD, d = i - ncs * DD;
    mT[d][ncs] = mask[i];
  }
  for (int i = tid; i < NCH * MDD; i += 256) {
    const int ncs = i / MDD, d = i - ncs * MDD;
    wT[d][ncs] = weight[i];
  }
  if (tid < NCH) bL[tid] = bias[tid];

  const int nc   = tid & 15;
  const int pix  = tid >> 4;
  const int base = (int)blockIdx.x * 16;

  // cooperative patch staging: 16 pixels x 27 taps, 'same' zero padding
  for (int i = tid; i < 16 * DD; i += 256) {
    const int pp = i / DD;
    const int d  = i - pp * DD;
    const int nn = base + pp;
    const int bb = nn >> 14;
    const int rr = nn & 16383;
    const int yy = rr >> 7;
    const int xx = rr & 127;
    const int c  = d / 9;
    const int ij = d - c * 9;
    const int di = ij / 3;
    const int dj = ij - di * 3;
    const int ys = yy + di - 1;
    const int xs = xx + dj - 1;
    const bool ok = ((unsigned)ys < (unsigned)HH) && ((unsigned)xs < (unsigned)WW);
    pL[pp][d] = ok ? xin[((bb * CCH + c) * HH + ys) * WW + xs] : 0.0f;
  }
  __syncthreads();

  const float t = bL[nc];

  // ---- build 27 exact keys + index payloads ----
  unsigned k[32], pay[32];
  #pragma unroll
  for (int d = 0; d < DD; ++d) {
    const float m = mT[d][nc] + pL[pix][d];
    k[d]   = f2key(__float_as_uint(m));
    pay[d] = (unsigned)d;
  }
  #pragma unroll
  for (int i = DD; i < 32; ++i) { k[i] = 0u; pay[i] = 0u; }

  // ---- Batcher merge-exchange sort, n=32, descending (191 CEs) ----
  {
    constexpr int P_[15][3] = {
      {16,16,0},{8,8,0},{8,8,8},{4,4,0},{4,12,4},{4,4,4},
      {2,2,0},{2,14,2},{2,6,2},{2,2,2},
      {1,1,0},{1,15,1},{1,7,1},{1,3,1},{1,1,1}};
    #pragma unroll
    for (int s = 0; s < 15; ++s) {
      const int p = P_[s][0], d = P_[s][1], r = P_[s][2];
      #pragma unroll
      for (int i = 0; i < 32 - d; ++i) {
        if ((i & p) == r) {
          const int l = i + d;
          const unsigned ka = k[i], kb = k[l];
          const unsigned pa = pay[i], pb = pay[l];
          const bool sw = (ka < kb);
          k[i] = sw ? kb : ka;    k[l] = sw ? ka : kb;
          pay[i] = sw ? pb : pa;  pay[l] = sw ? pa : pb;
        }
      }
    }
  }

  // ---- sign-split; park bottom half in LDS ----
  const int pk = tid * PSTR;
  unsigned tw[32];
  {
    unsigned pp0 = 0, pp1 = 0, pp2 = 0, pp3 = 0, pp4 = 0, pp5 = 0, pp6 = 0;
    #pragma unroll
    for (int i = 0; i < 32; ++i) {
      const bool neg = k[i] < 0x80000000u;      // m < 0 (sentinels: true)
      const unsigned tk  = neg ? ~k[i] : k[i];
      const unsigned p27 = pay[i] + DD;
      tw[i] = neg ? p27 : pay[i];
      if (i < DD) {
        const unsigned bw = neg ? pay[i] : p27; // the other side's index
        park[pk + i] = ~tk;                     // bk
        const unsigned sh = bw << (8 * (i & 3));
        if ((i >> 2) == 0) pp0 |= sh;
        else if ((i >> 2) == 1) pp1 |= sh;
        else if ((i >> 2) == 2) pp2 |= sh;
        else if ((i >> 2) == 3) pp3 |= sh;
        else if ((i >> 2) == 4) pp4 |= sh;
        else if ((i >> 2) == 5) pp5 |= sh;
        else pp6 |= sh;
      }
      k[i] = tk;
    }
    park[pk + 27] = pp0; park[pk + 28] = pp1; park[pk + 29] = pp2;
    park[pk + 30] = pp3; park[pk + 31] = pp4; park[pk + 32] = pp5;
    park[pk + 33] = pp6;
  }

  // ---- top: bitonic merge of 32, descending (keys + tw) ----
  #pragma unroll
  for (int j = 16; j >= 1; j >>= 1) {
    #pragma unroll
    for (int i = 0; i < 32; ++i) {
      if ((i & j) == 0) {
        const int l = i + j;
        const unsigned ka = k[i], kb = k[l];
        const unsigned pa = tw[i], pb = tw[l];
        const bool sw = (ka < kb);
        k[i] = sw ? kb : ka;   k[l] = sw ? ka : kb;
        tw[i] = sw ? pb : pa;  tw[l] = sw ? pa : pb;
      }
    }
  }

  // ---- top walk: positions 5..31 (0..4 are 0xFFFFFFFF sentinels) ----
  float acc = 0.0f;
  unsigned ykey = k[5];                 // max real candidate (li clipped to 0)
  #pragma unroll
  for (int pos = 5; pos < 32; ++pos) {
    acc += wT[tw[pos]][nc];
    ykey = (acc <= t) ? k[pos] : ykey;
  }

  // ---- bottom: reload park, merge, walk 0..26 (27..31 are zero sentinels) ----
  {
    unsigned bk[32], bw[32];
    const unsigned q0 = park[pk + 27], q1 = park[pk + 28], q2 = park[pk + 29],
                   q3 = park[pk + 30], q4 = park[pk + 31], q5 = park[pk + 32],
                   q6 = park[pk + 33];
    #pragma unroll
    for (int i = 0; i < DD; ++i) {
      bk[i] = park[pk + i];
      const unsigned q = (i >> 2) == 0 ? q0 : (i >> 2) == 1 ? q1 :
                         (i >> 2) == 2 ? q2 : (i >> 2) == 3 ? q3 :
                         (i >> 2) == 4 ? q4 : (i >> 2) == 5 ? q5 : q6;
      bw[i] = (q >> (8 * (i & 3))) & 0x3Fu;
    }
    #pragma unroll
    for (int i = DD; i < 32; ++i) { bk[i] = 0u; bw[i] = 0u; }

    #pragma unroll
    for (int j = 16; j >= 1; j >>= 1) {
      #pragma unroll
      for (int i = 0; i < 32; ++i) {
        if ((i & j) == 0) {
          const int l = i + j;
          const unsigned ka = bk[i], kb = bk[l];
          const unsigned pa = bw[i], pb = bw[l];
          const bool sw = (ka < kb);
          bk[i] = sw ? kb : ka;  bk[l] = sw ? ka : kb;
          bw[i] = sw ? pb : pa;  bw[l] = sw ? pa : pb;
        }
      }
    }
    #pragma unroll
    for (int pos = 0; pos < DD; ++pos) {
      acc += wT[bw[pos]][nc];
      ykey = (acc <= t) ? bk[pos] : ykey;
    }
  }

  // exact inverse of f2key
  const unsigned bits = (ykey & 0x80000000u) ? (ykey ^ 0x80000000u) : ~ykey;
  out[(base + pix) * NCH + nc] = __uint_as_float(bits);
}

extern "C" void kernel_launch(void* const* d_in, const int* in_sizes, int n_in,
                              void* d_out, int out_size, void* d_ws, size_t ws_size,
                              hipStream_t stream) {
  const float* x      = (const float*)d_in[0];
  const float* mask   = (const float*)d_in[1];
  const float* weight = (const float*)d_in[2];
  const float* bias   = (const float*)d_in[3];
  float* outp = (float*)d_out;

  dim3 grid(4096);   // 65536 pixels / 16 per block
  dim3 block(256);   // 16 pixels x 16 channels
  hipLaunchKernelGGL(wos_kernel, grid, block, 0, stream, x, mask, weight, bias, outp);
}

// Round 9
// 57.210 us; speedup vs baseline: 1.5576x; 1.1648x over previous
//
#include <hip/hip_runtime.h>

// Weighted order statistic, B=4,C=3,K=3,NC=16,H=W=128, D=27, MD=54.
// One thread per (pixel, nc).
//   1) keys = f2key(mask+patch) (exact 32-bit monotone map), payload = d;
//      Batcher merge-exchange sort of 32 slots (5 zero sentinels), DESC (191 CE).
//   2) sign-split: tk[i] = max(k[i], ~k[i]) (the |m| side; 5x 0xFFFFFFFF
//      sentinels), pack[i] = top_weight_idx | (bottom_weight_idx << 16)
//      where top = neg ? d+27 : d, bottom = the partner.
//   3) ONE 32-wide bitonic merge desc (tk is V-shaped/bitonic) — 80 CE.
//      KEY FACT: the bottom half of the 54-candidate order is free:
//      bottom[pos] = ~tk[31-pos], weight idx = pack[31-pos]>>16
//      (complement reverses order; the pair {v,-v} maps via ~).
//   4) walk top positions 5..31 then bottom 0..26 with ONE sequential f32
//      inclusive cumsum (bit-identical add order to the reference's
//      jnp.cumsum); select last position with acc <= bias; fallback =
//      top pos 5 (max candidate, li clipped to 0). Exact inverse f2key.
// Output layout: reference reshapes (b*hw, NC) -> (b,NC,h,w) without
// transpose, so flat order is (b, hw, nc) -> out[n*NCH + nc].

#define NCH 16
#define DD  27
#define MDD 54
#define HH  128
#define WW  128
#define CCH 3

__device__ __forceinline__ unsigned f2key(unsigned bits) {
  const unsigned s = (unsigned)((int)bits >> 31);
  return bits ^ (s | 0x80000000u);
}

__global__ __launch_bounds__(256) void wos_kernel(
    const float* __restrict__ xin,
    const float* __restrict__ mask,
    const float* __restrict__ weight,
    const float* __restrict__ bias,
    float* __restrict__ out)
{
  __shared__ float mT[DD][NCH];      // mask transposed [d][nc]
  __shared__ float wT[MDD][NCH];     // weights transposed [idx][nc]
  __shared__ float pL[16][DD + 1];   // patches (reads broadcast per pix group)
  __shared__ float bL[NCH];

  const int tid = threadIdx.x;
  for (int i = tid; i < NCH * DD; i += 256) {
    const int ncs = i / DD, d = i - ncs * DD;
    mT[d][ncs] = mask[i];
  }
  for (int i = tid; i < NCH * MDD; i += 256) {
    const int ncs = i / MDD, d = i - ncs * MDD;
    wT[d][ncs] = weight[i];
  }
  if (tid < NCH) bL[tid] = bias[tid];

  const int nc   = tid & 15;
  const int pix  = tid >> 4;
  const int base = (int)blockIdx.x * 16;

  // cooperative patch staging: 16 pixels x 27 taps, 'same' zero padding
  for (int i = tid; i < 16 * DD; i += 256) {
    const int pp = i / DD;
    const int d  = i - pp * DD;
    const int nn = base + pp;
    const int bb = nn >> 14;
    const int rr = nn & 16383;
    const int yy = rr >> 7;
    const int xx = rr & 127;
    const int c  = d / 9;
    const int ij = d - c * 9;
    const int di = ij / 3;
    const int dj = ij - di * 3;
    const int ys = yy + di - 1;
    const int xs = xx + dj - 1;
    const bool ok = ((unsigned)ys < (unsigned)HH) && ((unsigned)xs < (unsigned)WW);
    pL[pp][d] = ok ? xin[((bb * CCH + c) * HH + ys) * WW + xs] : 0.0f;
  }
  __syncthreads();

  const float t = bL[nc];

  // ---- build 27 exact keys + index payloads ----
  unsigned k[32], pay[32];
  #pragma unroll
  for (int d = 0; d < DD; ++d) {
    const float m = mT[d][nc] + pL[pix][d];
    k[d]   = f2key(__float_as_uint(m));
    pay[d] = (unsigned)d;
  }
  #pragma unroll
  for (int i = DD; i < 32; ++i) { k[i] = 0u; pay[i] = 0u; }

  // ---- Batcher merge-exchange sort, n=32, descending (191 CEs) ----
  {
    constexpr int P_[15][3] = {
      {16,16,0},{8,8,0},{8,8,8},{4,4,0},{4,12,4},{4,4,4},
      {2,2,0},{2,14,2},{2,6,2},{2,2,2},
      {1,1,0},{1,15,1},{1,7,1},{1,3,1},{1,1,1}};
    #pragma unroll
    for (int s = 0; s < 15; ++s) {
      const int p = P_[s][0], d = P_[s][1], r = P_[s][2];
      #pragma unroll
      for (int i = 0; i < 32 - d; ++i) {
        if ((i & p) == r) {
          const int l = i + d;
          const unsigned ka = k[i], kb = k[l];
          const unsigned pa = pay[i], pb = pay[l];
          const bool sw = (ka < kb);
          k[i] = sw ? kb : ka;    k[l] = sw ? ka : kb;
          pay[i] = sw ? pb : pa;  pay[l] = sw ? pa : pb;
        }
      }
    }
  }

  // ---- sign-split: tk = |m|-side key; pack = top_idx | bottom_idx<<16 ----
  unsigned tk[32], pack[32];
  #pragma unroll
  for (int i = 0; i < 32; ++i) {
    const bool neg = k[i] < 0x80000000u;    // m < 0 (sentinels: true)
    tk[i] = neg ? ~k[i] : k[i];
    const unsigned d27 = pay[i] + DD;
    const unsigned topi = neg ? d27 : pay[i];     // weight idx of larger side
    const unsigned boti = neg ? pay[i] : d27;     // weight idx of smaller side
    pack[i] = topi | (boti << 16);
  }

  // ---- one bitonic merge of 32, descending (tk is bitonic) ----
  #pragma unroll
  for (int j = 16; j >= 1; j >>= 1) {
    #pragma unroll
    for (int i = 0; i < 32; ++i) {
      if ((i & j) == 0) {
        const int l = i + j;
        const unsigned ka = tk[i], kb = tk[l];
        const unsigned pa = pack[i], pb = pack[l];
        const bool sw = (ka < kb);
        tk[i] = sw ? kb : ka;     tk[l] = sw ? ka : kb;
        pack[i] = sw ? pb : pa;   pack[l] = sw ? pa : pb;
      }
    }
  }

  // ---- walk: top positions 5..31, then bottom 0..26 (= ~tk[31-pos]) ----
  float acc = 0.0f;
  unsigned ykey = tk[5];               // max real candidate (li clipped to 0)
  #pragma unroll
  for (int pos = 5; pos < 32; ++pos) {
    acc += wT[pack[pos] & 0xFFFFu][nc];
    ykey = (acc <= t) ? tk[pos] : ykey;
  }
  #pragma unroll
  for (int pos = 0; pos < DD; ++pos) {
    const int src = 31 - pos;          // static index
    acc += wT[pack[src] >> 16][nc];
    const unsigned bkey = ~tk[src];
    ykey = (acc <= t) ? bkey : ykey;
  }

  // exact inverse of f2key
  const unsigned bits = (ykey & 0x80000000u) ? (ykey ^ 0x80000000u) : ~ykey;
  out[(base + pix) * NCH + nc] = __uint_as_float(bits);
}

extern "C" void kernel_launch(void* const* d_in, const int* in_sizes, int n_in,
                              void* d_out, int out_size, void* d_ws, size_t ws_size,
                              hipStream_t stream) {
  const float* x      = (const float*)d_in[0];
  const float* mask   = (const float*)d_in[1];
  const float* weight = (const float*)d_in[2];
  const float* bias   = (const float*)d_in[3];
  float* outp = (float*)d_out;

  dim3 grid(4096);   // 65536 pixels / 16 per block
  dim3 block(256);   // 16 pixels x 16 channels
  hipLaunchKernelGGL(wos_kernel, grid, block, 0, stream, x, mask, weight, bias, outp);
}

// Round 10
// 44.936 us; speedup vs baseline: 1.9830x; 1.2731x over previous
//
#include <hip/hip_runtime.h>

// Weighted order statistic, B=4,C=3,K=3,NC=16,H=W=128, D=27, MD=54.
// One thread per (pixel, nc). Candidates are the 27 pairs +/-|m_d| where
// m_d = mask[nc,d] + patch[d]. The full 54-candidate descending order is:
//   top    27: +|m| in descending |m| order
//   bottom 27: -|m| in ascending |m| order = reverse complement of top.
// So ONE Batcher merge-exchange sort (n=32, 191 CEs, 5 zero sentinels that
// sink to positions 27..31) of the exact |m|-keys (tk = bits|0x80000000,
// exact monotone map of |m|) with a packed payload
//   pack = top_weight_idx | (bottom_weight_idx << 16)
//   (m>=0: top=d, bottom=d+27; m<0: top=d+27, bottom=d)
// yields everything. Walk top positions 0..26 then bottom src 26..0
// (key = ~tk[src], weight idx = pack[src]>>16) with ONE sequential f32
// inclusive cumsum — bit-identical add order to the reference's jnp.cumsum.
// Select last position with acc <= bias; fallback = tk[0] (max candidate,
// li clipped to 0). Value reconstructed by the exact inverse of f2key.
// __launch_bounds__(256,4): 128-VGPR budget so sort arrays stay in VGPRs
// (R9's VGPR=44 showed AGPR demotion; R7's waves_per_eu(2,2) capped occ).
// Output layout: reference reshapes (b*hw, NC) -> (b,NC,h,w) without
// transpose, so flat order is (b, hw, nc) -> out[n*NCH + nc].

#define NCH 16
#define DD  27
#define MDD 54
#define HH  128
#define WW  128
#define CCH 3

__global__ __launch_bounds__(256, 4) void wos_kernel(
    const float* __restrict__ xin,
    const float* __restrict__ mask,
    const float* __restrict__ weight,
    const float* __restrict__ bias,
    float* __restrict__ out)
{
  __shared__ float mT[DD][NCH];      // mask transposed [d][nc]
  __shared__ float wT[MDD][NCH];     // weights transposed [idx][nc]
  __shared__ float pL[16][DD + 1];   // patches (reads broadcast per pix group)
  __shared__ float bL[NCH];

  const int tid = threadIdx.x;
  for (int i = tid; i < NCH * DD; i += 256) {
    const int ncs = i / DD, d = i - ncs * DD;
    mT[d][ncs] = mask[i];
  }
  for (int i = tid; i < NCH * MDD; i += 256) {
    const int ncs = i / MDD, d = i - ncs * MDD;
    wT[d][ncs] = weight[i];
  }
  if (tid < NCH) bL[tid] = bias[tid];

  const int nc   = tid & 15;
  const int pix  = tid >> 4;
  const int base = (int)blockIdx.x * 16;

  // cooperative patch staging: 16 pixels x 27 taps, 'same' zero padding
  for (int i = tid; i < 16 * DD; i += 256) {
    const int pp = i / DD;
    const int d  = i - pp * DD;
    const int nn = base + pp;
    const int bb = nn >> 14;
    const int rr = nn & 16383;
    const int yy = rr >> 7;
    const int xx = rr & 127;
    const int c  = d / 9;
    const int ij = d - c * 9;
    const int di = ij / 3;
    const int dj = ij - di * 3;
    const int ys = yy + di - 1;
    const int xs = xx + dj - 1;
    const bool ok = ((unsigned)ys < (unsigned)HH) && ((unsigned)xs < (unsigned)WW);
    pL[pp][d] = ok ? xin[((bb * CCH + c) * HH + ys) * WW + xs] : 0.0f;
  }
  __syncthreads();

  const float t = bL[nc];

  // ---- build 27 exact |m|-keys + packed dual weight indices ----
  unsigned tk[32], pack[32];
  #pragma unroll
  for (int d = 0; d < DD; ++d) {
    const float m = mT[d][nc] + pL[pix][d];
    const unsigned bits = __float_as_uint(m);
    tk[d] = bits | 0x80000000u;                    // f2key(|m|), exact
    const unsigned pos_pack = (unsigned)d | ((unsigned)(d + DD) << 16);
    const unsigned neg_pack = (unsigned)(d + DD) | ((unsigned)d << 16);
    pack[d] = ((int)bits < 0) ? neg_pack : pos_pack;
  }
  #pragma unroll
  for (int i = DD; i < 32; ++i) { tk[i] = 0u; pack[i] = 0u; }

  // ---- Batcher merge-exchange sort, n=32, descending (191 CEs) ----
  {
    constexpr int P_[15][3] = {
      {16,16,0},{8,8,0},{8,8,8},{4,4,0},{4,12,4},{4,4,4},
      {2,2,0},{2,14,2},{2,6,2},{2,2,2},
      {1,1,0},{1,15,1},{1,7,1},{1,3,1},{1,1,1}};
    #pragma unroll
    for (int s = 0; s < 15; ++s) {
      const int p = P_[s][0], d = P_[s][1], r = P_[s][2];
      #pragma unroll
      for (int i = 0; i < 32 - d; ++i) {
        if ((i & p) == r) {
          const int l = i + d;
          const unsigned ka = tk[i], kb = tk[l];
          const unsigned pa = pack[i], pb = pack[l];
          const bool sw = (ka < kb);
          tk[i] = sw ? kb : ka;     tk[l] = sw ? ka : kb;
          pack[i] = sw ? pb : pa;   pack[l] = sw ? pa : pb;
        }
      }
    }
  }

  // ---- walk: top positions 0..26 (+|m| desc), then bottom (= ~tk[26-pos]) ----
  float acc = 0.0f;
  unsigned ykey = tk[0];               // max real candidate (li clipped to 0)
  #pragma unroll
  for (int pos = 0; pos < DD; ++pos) {
    acc += wT[pack[pos] & 0xFFFFu][nc];
    ykey = (acc <= t) ? tk[pos] : ykey;
  }
  #pragma unroll
  for (int pos = 0; pos < DD; ++pos) {
    const int src = DD - 1 - pos;      // static index
    acc += wT[pack[src] >> 16][nc];
    const unsigned bkey = ~tk[src];
    ykey = (acc <= t) ? bkey : ykey;
  }

  // exact inverse of f2key
  const unsigned bits = (ykey & 0x80000000u) ? (ykey ^ 0x80000000u) : ~ykey;
  out[(base + pix) * NCH + nc] = __uint_as_float(bits);
}

extern "C" void kernel_launch(void* const* d_in, const int* in_sizes, int n_in,
                              void* d_out, int out_size, void* d_ws, size_t ws_size,
                              hipStream_t stream) {
  const float* x      = (const float*)d_in[0];
  const float* mask   = (const float*)d_in[1];
  const float* weight = (const float*)d_in[2];
  const float* bias   = (const float*)d_in[3];
  float* outp = (float*)d_out;

  dim3 grid(4096);   // 65536 pixels / 16 per block
  dim3 block(256);   // 16 pixels x 16 channels
  hipLaunchKernelGGL(wos_kernel, grid, block, 0, stream, x, mask, weight, bias, outp);
}